// Round 1
// baseline (591.758 us; speedup 1.0000x reference)
//
#include <hip/hip_runtime.h>

// Segmented mean: x[N][64] fp32, seg[N] int32 (sorted, contiguous), len[B] int32.
// out[B][64] = segment_sum(x) / len.
//
// Memory-bound: 256 MB read -> ~41 us floor at 6.3 TB/s.
// Structure exploited: min segment length ~8100 rows >> ROWS_PER_BLOCK, so a
// 512-row block spans <=2 segments; ~63/2048 blocks contain a boundary.
// Fast path: NO per-row seg loads, NO per-row branches -- pure nontemporal
// float4 streaming adds with one uniform `r < boundary` predicate.
// Accumulates directly into `out` (no d_ws usage at all -- the harness's 1 GiB
// workspace poison fill was the largest dispatch in the profile), and the last
// block performs the division in-place (fused; self-cleaning device counter).

#define D 64
#define ROWS_PER_BLOCK 512
#define NTHREADS 256

typedef float f32x4 __attribute__((ext_vector_type(4)));

// Zero-initialized at module load; the last block resets it to 0 for the next
// graph replay (stream-ordered, so no race across replays).
__device__ int g_done_counter = 0;

__global__ __launch_bounds__(NTHREADS) void seg_mean_kernel(
    const float* __restrict__ x,
    const int*   __restrict__ seg,
    const int*   __restrict__ len,
    float*       __restrict__ out,    // [B][D], pre-zeroed; accumulator + output
    int n_rows, int total)
{
    __shared__ float lacc[2][D];
    __shared__ int sBoundary, sNb, sIsLast;

    const int tid = threadIdx.x;
    const int r0  = blockIdx.x * ROWS_PER_BLOCK;
    int r1 = r0 + ROWS_PER_BLOCK;
    if (r1 > n_rows) r1 = n_rows;

    // thread layout: 16 col-groups (float4) x 16 row-lanes
    const int col     = (tid & 15) * 4;
    const int rowlane = tid >> 4;

    if (r0 < n_rows) {   // block-uniform
        const int s0 = seg[r0];
        const int sN = seg[r1 - 1];

        for (int i = tid; i < 2 * D; i += NTHREADS) ((float*)lacc)[i] = 0.0f;
        if (tid == 0) { sBoundary = r1; sNb = 0; }
        __syncthreads();

        int boundary = r1, nb = 0;
        if (s0 != sN) {  // block-uniform: only ~63/2048 blocks scan
            for (int i = r0 + 1 + tid; i < r1; i += NTHREADS) {
                if (seg[i] != seg[i - 1]) { atomicAdd(&sNb, 1); atomicMin(&sBoundary, i); }
            }
            __syncthreads();
            boundary = sBoundary;
            nb       = sNb;
        }

        if (nb <= 1) {
            // ---- fast path: streaming loop, no seg loads, uniform predicate ----
            f32x4 a0 = {0.f, 0.f, 0.f, 0.f};
            f32x4 a1 = {0.f, 0.f, 0.f, 0.f};
            for (int r = r0 + rowlane; r < r1; r += 16) {
                const f32x4 v = __builtin_nontemporal_load(
                    reinterpret_cast<const f32x4*>(x + (size_t)r * D + col));
                if (r < boundary) { a0 += v; } else { a1 += v; }
            }
            atomicAdd(&lacc[0][col + 0], a0.x);
            atomicAdd(&lacc[0][col + 1], a0.y);
            atomicAdd(&lacc[0][col + 2], a0.z);
            atomicAdd(&lacc[0][col + 3], a0.w);
            if (boundary < r1) {
                atomicAdd(&lacc[1][col + 0], a1.x);
                atomicAdd(&lacc[1][col + 1], a1.y);
                atomicAdd(&lacc[1][col + 2], a1.z);
                atomicAdd(&lacc[1][col + 3], a1.w);
            }
            __syncthreads();
            if (tid < D) {
                atomicAdd(&out[(size_t)s0 * D + tid], lacc[0][tid]);
                if (boundary < r1)
                    atomicAdd(&out[(size_t)sN * D + tid], lacc[1][tid]);
            }
        } else {
            // ---- general fallback (not expected on this data) ----
            f32x4 a = {0.f, 0.f, 0.f, 0.f};
            int cur = -1;
            for (int r = r0 + rowlane; r < r1; r += 16) {
                const int s = seg[r];
                const f32x4 v = *reinterpret_cast<const f32x4*>(x + (size_t)r * D + col);
                if (s != cur) {
                    if (cur >= 0) {
                        atomicAdd(&out[(size_t)cur * D + col + 0], a.x);
                        atomicAdd(&out[(size_t)cur * D + col + 1], a.y);
                        atomicAdd(&out[(size_t)cur * D + col + 2], a.z);
                        atomicAdd(&out[(size_t)cur * D + col + 3], a.w);
                    }
                    a = {0.f, 0.f, 0.f, 0.f};
                    cur = s;
                }
                a += v;
            }
            if (cur >= 0) {
                atomicAdd(&out[(size_t)cur * D + col + 0], a.x);
                atomicAdd(&out[(size_t)cur * D + col + 1], a.y);
                atomicAdd(&out[(size_t)cur * D + col + 2], a.z);
                atomicAdd(&out[(size_t)cur * D + col + 3], a.w);
            }
        }
    }

    // ---- completion detection + fused divide (last block) ----
    __threadfence();       // release: make this thread's global atomics visible
    __syncthreads();       // all threads of block done
    if (tid == 0) {
        const int prev = __hip_atomic_fetch_add(&g_done_counter, 1,
                             __ATOMIC_ACQ_REL, __HIP_MEMORY_SCOPE_AGENT);
        sIsLast = (prev == (int)gridDim.x - 1);
    }
    __syncthreads();
    if (sIsLast) {         // block-uniform
        if (tid == 0)      // self-clean for the next graph replay
            __hip_atomic_store(&g_done_counter, 0,
                               __ATOMIC_RELAXED, __HIP_MEMORY_SCOPE_AGENT);
        for (int i = tid; i < total; i += NTHREADS) {
            // agent-scope atomic load: read the coherence point, not a
            // possibly-stale per-XCD L2 line (G16)
            const float v = __hip_atomic_load(&out[i],
                                __ATOMIC_RELAXED, __HIP_MEMORY_SCOPE_AGENT);
            out[i] = v / (float)len[i >> 6];   // i>>6 == segment (D=64)
        }
    }
}

extern "C" void kernel_launch(void* const* d_in, const int* in_sizes, int n_in,
                              void* d_out, int out_size, void* d_ws, size_t ws_size,
                              hipStream_t stream) {
    const float* x   = (const float*)d_in[0];
    const int*   seg = (const int*)d_in[1];
    const int*   len = (const int*)d_in[2];
    float*       out = (float*)d_out;

    const int n_rows = in_sizes[1];       // N = 1048576
    const int B      = in_sizes[2];       // 64
    const int total  = B * D;             // 4096 == out_size

    // out doubles as the accumulator: zero it (out is poisoned before each call)
    hipMemsetAsync(out, 0, (size_t)total * sizeof(float), stream);

    const int grid = (n_rows + ROWS_PER_BLOCK - 1) / ROWS_PER_BLOCK;  // 2048
    seg_mean_kernel<<<grid, NTHREADS, 0, stream>>>(x, seg, len, out, n_rows, total);
}